// Round 8
// baseline (332.081 us; speedup 1.0000x reference)
//
#include <hip/hip_runtime.h>

// LCT FK-migration: 3D FFT(512,256,256) -> Stolt trilinear resample -> 3D IFFT -> |.|^2
// Single 256 MiB workspace buffer V = [512][256][256] cpx, flat (z<<16)+(y<<8)+x.
// x/y spectra stored FFTSHIFTED with the half-pixel Stolt x/y blurs folded into the
// forward x/y FFT stores (ix = xs-0.5, iy = ys-0.5 exactly => fx=fy=0.5 fixed blur).
// Z-STAGE FUSED, SINGLE-DEST (k_fftz_fused): block for dest column (y,x-tile) loads its
// partner source column ((y+128)&255,(x+128)&255) from planes 0..255 into ONE 64 KiB
// LDS buffer, fwd 512-pt FFT, z-only Stolt gather into registers, reuse the buffer for
// the inverse FFT, and writes dest to planes 256..511 (disjoint from all source reads
// -> race-free, and 64 KiB keeps 2 blocks/CU resident). Each source column is
// forward-FFT'd exactly once (by its partner's block). Inverse y and inverse x+|.|^2
// then run on planes 256..511 via an offset base pointer.

typedef float2 cpx;

__device__ float2 g_tw[512];   // exp(-2*pi*i*k/512), k in [0,512)

__device__ __forceinline__ cpx cadd(cpx a, cpx b){ return make_float2(a.x+b.x, a.y+b.y); }
__device__ __forceinline__ cpx csub(cpx a, cpx b){ return make_float2(a.x-b.x, a.y-b.y); }
__device__ __forceinline__ cpx cmul(cpx a, cpx b){ return make_float2(a.x*b.x - a.y*b.y, a.x*b.y + a.y*b.x); }

// ---------------- twiddle table (double-computed for accuracy) ----------------
__global__ void k_tw(){
    int j = threadIdx.x;                        // 512 threads
    double a = -2.0*3.14159265358979323846*(double)j/512.0;
    g_tw[j] = make_float2((float)cos(a), (float)sin(a));
}

template<bool INV>
__device__ __forceinline__ cpx twmul(cpx a, int k){
    cpx w = g_tw[k & 511];
    if (INV) w.y = -w.y;
    return cmul(a, w);
}

// ---------------- radix-4 DIF butterfly (in-register) ----------------
template<bool INV>
__device__ __forceinline__ void dft4(cpx* x){
    cpx e0 = cadd(x[0], x[2]), e1 = csub(x[0], x[2]);
    cpx o0 = cadd(x[1], x[3]), o1 = csub(x[1], x[3]);
    x[0] = cadd(e0, o0);
    x[2] = csub(e0, o0);
    if (!INV){ x[1] = make_float2(e1.x + o1.y, e1.y - o1.x);
               x[3] = make_float2(e1.x - o1.y, e1.y + o1.x); }
    else     { x[1] = make_float2(e1.x - o1.y, e1.y + o1.x);
               x[3] = make_float2(e1.x + o1.y, e1.y - o1.x); }
}

// ---------------- radix-8 DIF butterfly (in-register) ----------------
template<bool INV>
__device__ __forceinline__ void dft8(cpx* x){
    const float s = 0.70710678118654752440f;
    cpx e0 = cadd(x[0], x[4]), e2 = csub(x[0], x[4]);
    cpx e1 = cadd(x[2], x[6]), e3 = csub(x[2], x[6]);
    cpx E0 = cadd(e0, e1), E2 = csub(e0, e1);
    cpx E1, E3;
    if (!INV){ E1 = make_float2(e2.x + e3.y, e2.y - e3.x);
               E3 = make_float2(e2.x - e3.y, e2.y + e3.x); }
    else     { E1 = make_float2(e2.x - e3.y, e2.y + e3.x);
               E3 = make_float2(e2.x + e3.y, e2.y - e3.x); }
    cpx o0 = cadd(x[1], x[5]), o2 = csub(x[1], x[5]);
    cpx o1 = cadd(x[3], x[7]), o3 = csub(x[3], x[7]);
    cpx O0 = cadd(o0, o1), O2 = csub(o0, o1);
    cpx O1, O3;
    if (!INV){ O1 = make_float2(o2.x + o3.y, o2.y - o3.x);
               O3 = make_float2(o2.x - o3.y, o2.y + o3.x); }
    else     { O1 = make_float2(o2.x - o3.y, o2.y + o3.x);
               O3 = make_float2(o2.x + o3.y, o2.y - o3.x); }
    cpx W1, W2, W3;
    if (!INV){
        W1 = make_float2(s*(O1.x + O1.y), s*(O1.y - O1.x));
        W2 = make_float2(O2.y, -O2.x);
        W3 = make_float2(s*(O3.y - O3.x), -s*(O3.x + O3.y));
    } else {
        W1 = make_float2(s*(O1.x - O1.y), s*(O1.x + O1.y));
        W2 = make_float2(-O2.y, O2.x);
        W3 = make_float2(-s*(O3.x + O3.y), s*(O3.x - O3.y));
    }
    x[0] = cadd(E0, O0); x[4] = csub(E0, O0);
    x[1] = cadd(E1, W1); x[5] = csub(E1, W1);
    x[2] = cadd(E2, W2); x[6] = csub(E2, W2);
    x[3] = cadd(E3, W3); x[7] = csub(E3, W3);
}

// ---------------- one radix-8 DIF stage of a 512-pt FFT in LDS (layout s[e*16+c]) ----------------
template<bool INV, int STAGE>
__device__ __forceinline__ void zstage(cpx* s, int c, int idx){
    cpx x[8];
    if (STAGE == 0){
        int j = idx;                             // stride 64, tw W_512^{j*r}
        #pragma unroll
        for (int t = 0; t < 8; ++t) x[t] = s[(j + (t << 6))*16 + c];
        dft8<INV>(x);
        #pragma unroll
        for (int r = 1; r < 8; ++r) x[r] = twmul<INV>(x[r], j*r);
        #pragma unroll
        for (int r = 0; r < 8; ++r) s[(j + (r << 6))*16 + c] = x[r];
    } else if (STAGE == 1){
        int j = idx & 7, g = (idx >> 3) << 6;    // stride 8, tw W_512^{8*j*r}
        #pragma unroll
        for (int t = 0; t < 8; ++t) x[t] = s[(g + j + (t << 3))*16 + c];
        dft8<INV>(x);
        #pragma unroll
        for (int r = 1; r < 8; ++r) x[r] = twmul<INV>(x[r], 8*j*r);
        #pragma unroll
        for (int r = 0; r < 8; ++r) s[(g + j + (r << 3))*16 + c] = x[r];
    } else {
        int g = idx << 3;                        // stride 1, no twiddle
        #pragma unroll
        for (int t = 0; t < 8; ++t) x[t] = s[(g + t)*16 + c];
        dft8<INV>(x);
        #pragma unroll
        for (int r = 0; r < 8; ++r) s[(g + r)*16 + c] = x[r];
    }
}

// ---------------- z-only Stolt gather from an in-LDS fwd spectrum (digit-reversed order) ----------------
// buf holds bins b in [0,512) at position rev8(b); gather needs bins z0-256, z1-256 (in [0,255]).
__device__ __forceinline__ cpx zgather(const cpx* __restrict__ buf, int zd, float rxy, int c){
    if (!zd) return make_float2(0.0f, 0.0f);     // t[:, :M+1] = 0 plane
    float gz = (float)zd*(1.0f/256.0f);
    float gzn = sqrtf(rxy + gz*gz);
    float iz = ((gzn + 1.0f)*512.0f - 1.0f)*0.5f;
    float fiz = floorf(iz);
    int iz0 = (int)fiz;                          // in [256, ~536)
    float fz = iz - fiz;
    float sc = gz/(gzn + 1e-8f);
    int b0 = (iz0 < 511 ? iz0 : 511) - 256;
    int b1 = ((iz0 + 1) < 511 ? (iz0 + 1) : 511) - 256;
    float w0 = (iz0     <= 511) ? (1.0f - fz)*sc : 0.0f;
    float w1 = (iz0 + 1 <= 511) ? fz*sc : 0.0f;
    int p0 = ((b0 & 7) << 6) | (b0 & 56) | (b0 >> 6);
    int p1 = ((b1 & 7) << 6) | (b1 & 56) | (b1 >> 6);
    cpx a = buf[p0*16 + c];
    cpx b = buf[p1*16 + c];
    return make_float2(a.x*w0 + b.x*w1, a.y*w0 + b.y*w1);
}

// ---------------- in-LDS radix-2 FFT, layout s[line][elem], 2 lines of 256 ----------------
template<bool INV>
__device__ __forceinline__ void fft_rows2(cpx* s, const cpx* ltw, int tid){
    const int L2LEN = 8, LEN = 256;
    #pragma unroll
    for (int st = 0; st < L2LEN; ++st){
        int lh = L2LEN - 1 - st;
        int half = 1 << lh;
        int tws = 512 >> (L2LEN - st);
        int l  = tid >> (L2LEN - 1);
        int bf = tid & ((LEN/2) - 1);
        int j  = bf & (half - 1);
        int i0 = ((bf >> lh) << (lh + 1)) | j;
        cpx u = s[l*LEN + i0], v = s[l*LEN + i0 + half];
        cpx w = ltw[j*tws];
        if (INV) w.y = -w.y;
        s[l*LEN + i0]        = cadd(u, v);
        s[l*LEN + i0 + half] = cmul(csub(u, v), w);
        __syncthreads();
    }
    for (int i = tid; i < 2*LEN; i += 256){     // bit-reversal -> natural order
        int l = i >> L2LEN, k = i & (LEN - 1);
        int r = __brev((unsigned)k) >> (32 - L2LEN);
        if (r > k){ cpx a = s[l*LEN + k]; s[l*LEN + k] = s[l*LEN + r]; s[l*LEN + r] = a; }
    }
    __syncthreads();
}

// ---------------- forward x-FFT fused with fill; store x-fftshifted AND x-half-blurred ----------------
__global__ __launch_bounds__(256) void k_fft_x_fill(const float* __restrict__ feat, cpx* __restrict__ V){
    __shared__ cpx s[2*256];
    __shared__ cpx ltw[256];
    int tid = threadIdx.x;
    ltw[tid] = g_tw[tid];
    int line0 = blockIdx.x << 1;                 // line = z*128 + y, z<256, y<128
    {
        int l = tid >> 7, e = tid & 127;
        int line = line0 + l;
        int z = line >> 7;
        float g = (float)z*(1.0f/255.0f);
        float v = feat[(line << 7) + e]*g*g;     // feat[z][y][x]
        v = v > 0.0f ? sqrtf(v) : 0.0f;
        s[l*256 + e]       = make_float2(v, 0.0f);
        s[l*256 + e + 128] = make_float2(0.0f, 0.0f);
    }
    __syncthreads();
    fft_rows2<false>(s, ltw, tid);
    {   // store blurred, float4 (positions 2f, 2f+1) per thread
        int l = tid >> 7, f = tid & 127;
        int line = line0 + l;
        int base = ((line >> 7) << 16) + ((line & 127) << 8);
        const float4* srow = (const float4*)(s + l*256);
        float4 A = srow[f ^ 64];                 // F_s[2f], F_s[2f+1]
        float4 B = make_float4(0.0f, 0.0f, 0.0f, 0.0f);
        if (f) B = srow[(f - 1) ^ 64];           // .zw = F_s[2f-1]
        float4 o;
        o.x = 0.5f*(B.z + A.x); o.y = 0.5f*(B.w + A.y);
        o.z = 0.5f*(A.x + A.z); o.w = 0.5f*(A.y + A.w);
        ((float4*)(V + base))[f] = o;
    }
}

// ---------------- final inverse x-FFT fused with |.|^2, crop x<128 ----------------
__global__ __launch_bounds__(256) void k_fft_x_inv_mag(const cpx* __restrict__ W,
                                                       float* __restrict__ out){
    __shared__ cpx s[2*256];
    __shared__ cpx ltw[256];
    int tid = threadIdx.x;
    ltw[tid] = g_tw[tid];
    int line0 = blockIdx.x << 1;
    {   // load 2 cpx per thread
        int l = tid >> 7, f4c = tid & 127;
        int line = line0 + l;
        int base = ((line >> 7) << 16) + ((line & 127) << 8);
        ((float4*)(s + l*256))[f4c] = ((const float4*)(W + base))[f4c];
    }
    __syncthreads();
    fft_rows2<true>(s, ltw, tid);
    {
        int l = tid >> 7, e = tid & 127;
        int line = line0 + l;
        int z = line >> 7, y = line & 127;
        cpx v = s[l*256 + e];
        const float SC2 = (1.0f/33554432.0f)*(1.0f/33554432.0f);   // (1/(512*256*256))^2
        out[(z*128 + y)*128 + e] = (v.x*v.x + v.y*v.y)*SC2;
    }
}

// ---------------- FFT along y: 256 pts = 4 radix-4 DIF stages, tile 16 x, fixed z ----------------
// Forward: store y-fftshifted AND y-half-blurred: pos e = 0.5*(F_s[e-1]+F_s[e]), F_s[-1]=0.
// Inverse: plain store, crop y<128.
template<bool INV, bool HALF_IN, bool HALF_OUT>
__global__ __launch_bounds__(1024) void k_fft_y(cpx* __restrict__ V){
    __shared__ cpx s[256*16];                   // 32 KiB
    int tid = threadIdx.x;
    int z  = blockIdx.x >> 4;
    int x0 = (blockIdx.x & 15) << 4;
    int base = (z << 16) + x0;
    const int YIN = HALF_IN ? 128 : 256;
    for (int i = tid; i < YIN*8; i += 1024){     // float4: 8 units of 2 cpx per row
        int f4c = i & 7, e = i >> 3;
        ((float4*)(s + e*16))[f4c] = ((const float4*)(V + base + (e << 8)))[f4c];
    }
    if (HALF_IN){
        for (int i = tid; i < 128*16; i += 1024){
            int c = i & 15, e = (i >> 4) + 128;
            s[e*16 + c] = make_float2(0.0f, 0.0f);
        }
    }
    __syncthreads();
    int c = tid & 15, idx = tid >> 4;
    cpx x[4];
    {   // stage 0: stride 64, tw W_512^{2*j*r}
        int j = idx;
        #pragma unroll
        for (int t = 0; t < 4; ++t) x[t] = s[(j + (t << 6))*16 + c];
        dft4<INV>(x);
        #pragma unroll
        for (int r = 1; r < 4; ++r) x[r] = twmul<INV>(x[r], 2*j*r);
        #pragma unroll
        for (int r = 0; r < 4; ++r) s[(j + (r << 6))*16 + c] = x[r];
    }
    __syncthreads();
    {   // stage 1: stride 16, tw W_512^{8*j*r}
        int j = idx & 15, g = (idx >> 4) << 6;
        #pragma unroll
        for (int t = 0; t < 4; ++t) x[t] = s[(g + j + (t << 4))*16 + c];
        dft4<INV>(x);
        #pragma unroll
        for (int r = 1; r < 4; ++r) x[r] = twmul<INV>(x[r], 8*j*r);
        #pragma unroll
        for (int r = 0; r < 4; ++r) s[(g + j + (r << 4))*16 + c] = x[r];
    }
    __syncthreads();
    {   // stage 2: stride 4, tw W_512^{32*j*r}
        int j = idx & 3, g = (idx >> 2) << 4;
        #pragma unroll
        for (int t = 0; t < 4; ++t) x[t] = s[(g + j + (t << 2))*16 + c];
        dft4<INV>(x);
        #pragma unroll
        for (int r = 1; r < 4; ++r) x[r] = twmul<INV>(x[r], 32*j*r);
        #pragma unroll
        for (int r = 0; r < 4; ++r) s[(g + j + (r << 2))*16 + c] = x[r];
    }
    __syncthreads();
    {   // stage 3: stride 1, no twiddle
        int g = idx << 2;
        #pragma unroll
        for (int t = 0; t < 4; ++t) x[t] = s[(g + t)*16 + c];
        dft4<INV>(x);
        #pragma unroll
        for (int r = 0; r < 4; ++r) s[(g + r)*16 + c] = x[r];
    }
    __syncthreads();
    const int YOUT = HALF_OUT ? 128 : 256;
    for (int i = tid; i < YOUT*8; i += 1024){
        int f4c = i & 7, e = i >> 3;
        if (!INV){
            // blurred shifted store: pos e = 0.5*(F_s[e-1] + F_s[e]); F_s[q] at row rev4(q)^2
            int p0 = (((e & 3) << 6) | (((e >> 2) & 3) << 4) | (((e >> 4) & 3) << 2) | (e >> 6)) ^ 2;
            float4 S0 = ((const float4*)(s + p0*16))[f4c];
            float4 S1 = make_float4(0.0f, 0.0f, 0.0f, 0.0f);
            if (e){
                int em = e - 1;
                int p1 = (((em & 3) << 6) | (((em >> 2) & 3) << 4) | (((em >> 4) & 3) << 2) | (em >> 6)) ^ 2;
                S1 = ((const float4*)(s + p1*16))[f4c];
            }
            float4 o;
            o.x = 0.5f*(S0.x + S1.x); o.y = 0.5f*(S0.y + S1.y);
            o.z = 0.5f*(S0.z + S1.z); o.w = 0.5f*(S0.w + S1.w);
            ((float4*)(V + base + (e << 8)))[f4c] = o;
        } else {
            int p = ((e & 3) << 6) | (((e >> 2) & 3) << 4) | (((e >> 4) & 3) << 2) | (e >> 6);
            ((float4*)(V + base + (e << 8)))[f4c] = ((const float4*)(s + p*16))[f4c];
        }
    }
}

// ---------------- FUSED z-stage, single-dest: fwd FFT of partner + gather + inv FFT ----------------
// Block (yD, x0D): source column (yS,x0S) = ((yD+128)&255, (x0D+128)&255). One 64 KiB
// buffer: fwd FFT source (read planes 0..255), gather dest into regs, reuse buffer for
// inverse FFT, write dest to planes 256..511. 2 blocks/CU resident.
__global__ __launch_bounds__(1024, 8) void k_fftz_fused(cpx* __restrict__ V){
    __shared__ cpx buf[512*16];                 // 64 KiB
    int tid = threadIdx.x;
    int yD  = blockIdx.x >> 4;                  // 0..255
    int x0D = (blockIdx.x & 15) << 4;
    int yS  = (yD + 128) & 255;
    int x0S = (x0D + 128) & 255;
    int baseD = (yD << 8) + x0D;
    int baseS = (yS << 8) + x0S;
    // load source column planes 0..255, zero-pad upper half
    for (int i = tid; i < 256*8; i += 1024){
        int f4c = i & 7, e = i >> 3;
        ((float4*)(buf + e*16))[f4c] = ((const float4*)(V + baseS + (e << 16)))[f4c];
    }
    for (int i = tid; i < 256*16; i += 1024){
        int cc = i & 15, e = (i >> 4) + 256;
        buf[e*16 + cc] = make_float2(0.0f, 0.0f);
    }
    __syncthreads();
    int c = tid & 15, idx = tid >> 4;
    // forward 512-pt FFT of the source column (output left digit-reversed in LDS)
    zstage<false,0>(buf, c, idx); __syncthreads();
    zstage<false,1>(buf, c, idx); __syncthreads();
    zstage<false,2>(buf, c, idx); __syncthreads();
    // Stolt gather for dest (zd = idx + k*64); grid coords come from SOURCE position
    float gx = (float)(x0S + c - 128)*(1.0f/128.0f);
    float gy = (float)(yS - 128)*(1.0f/128.0f);
    float rxy = 0.1024f*(gx*gx + gy*gy);
    cpx rg[4];
    #pragma unroll
    for (int k = 0; k < 4; ++k)
        rg[k] = zgather(buf, idx + (k << 6), rxy, c);
    __syncthreads();
    // rewrite buffer with gathered line (natural zd order), zero upper half
    #pragma unroll
    for (int k = 0; k < 4; ++k)
        buf[(idx + (k << 6))*16 + c] = rg[k];
    for (int i = tid; i < 256*16; i += 1024){
        int cc = i & 15, e = (i >> 4) + 256;
        buf[e*16 + cc] = make_float2(0.0f, 0.0f);
    }
    __syncthreads();
    // inverse 512-pt FFT
    zstage<true,0>(buf, c, idx); __syncthreads();
    zstage<true,1>(buf, c, idx); __syncthreads();
    zstage<true,2>(buf, c, idx); __syncthreads();
    // write dest planes 256..511 (digit-reversal resolved at store)
    for (int i = tid; i < 256*8; i += 1024){
        int f4c = i & 7, e = i >> 3;
        int p = ((e & 7) << 6) | (e & 56) | (e >> 6);
        ((float4*)(V + baseD + ((e + 256) << 16)))[f4c] = ((const float4*)(buf + p*16))[f4c];
    }
}

extern "C" void kernel_launch(void* const* d_in, const int* in_sizes, int n_in,
                              void* d_out, int out_size, void* d_ws, size_t ws_size,
                              hipStream_t stream){
    const float* feat = (const float*)d_in[0];   // [1,1,256,128,128] f32; tbes=0, tens=256
    float* out = (float*)d_out;                  // [1,1,256,128,128] f32

    const size_t WS_NEED = (size_t)512*256*256*8;   // 268,435,456 B exactly
    if (ws_size < WS_NEED){
        hipMemsetAsync(d_out, 0, (size_t)out_size*sizeof(float), stream);
        return;
    }
    cpx* V  = (cpx*)d_ws;
    cpx* Vu = V + (size_t)256*65536;             // planes 256..511 (post-z result)

    k_tw<<<1, 512, 0, stream>>>();
    // forward x (+fill,+x-blur) and y (+y-blur), stored fftshifted, planes 0..255
    k_fft_x_fill<<<16384, 256, 0, stream>>>(feat, V);               // lines z<256,y<128
    k_fft_y<false, true, false><<<4096, 1024, 0, stream>>>(V);      // z<256; y<128 in, full blurred y out
    // fused z-stage: reads planes 0..255 (partner column), writes planes 256..511
    k_fftz_fused<<<4096, 1024, 0, stream>>>(V);
    // inverse y + inverse x (+|.|^2) on planes 256..511 via offset base pointer
    k_fft_y<true, false, true><<<4096, 1024, 0, stream>>>(Vu);      // full y in, y<128 out
    k_fft_x_inv_mag<<<16384, 256, 0, stream>>>(Vu, out);            // full x in, |.|^2, x<128
}

// Round 9
// 281.205 us; speedup vs baseline: 1.1809x; 1.1809x over previous
//
#include <hip/hip_runtime.h>

// LCT FK-migration: 3D FFT(512,256,256) -> Stolt trilinear resample -> 3D IFFT -> |.|^2
// Single 256 MiB workspace buffer V = [512][256][256] cpx, flat (z<<16)+(y<<8)+x.
// x/y spectra stored FFTSHIFTED with the half-pixel Stolt x/y blurs folded into the
// forward x/y FFT stores (ix = xs-0.5, iy = ys-0.5 exactly => fx=fy=0.5 fixed blur).
// Z-stage SPLIT (round-7/8 fusion experiments both lost to this): k_fft_z_fwd writes
// shifted z-spectrum to planes 256..511; k_stolt_fftz_inv does z-only gather + inverse
// z-FFT, writing planes 0..255. Inverse y (crop y<128) and inverse x + |.|^2 (crop
// x<128) finish. x-kernels use the radix-4 template (4 lines/block, 4 stages).

typedef float2 cpx;

__device__ float2 g_tw[512];   // exp(-2*pi*i*k/512), k in [0,512)

__device__ __forceinline__ cpx cadd(cpx a, cpx b){ return make_float2(a.x+b.x, a.y+b.y); }
__device__ __forceinline__ cpx csub(cpx a, cpx b){ return make_float2(a.x-b.x, a.y-b.y); }
__device__ __forceinline__ cpx cmul(cpx a, cpx b){ return make_float2(a.x*b.x - a.y*b.y, a.x*b.y + a.y*b.x); }

// base-4 digit reversal of an 8-bit index
__device__ __forceinline__ int rev4_8(int k){
    return ((k & 3) << 6) | ((k & 12) << 2) | ((k >> 2) & 12) | (k >> 6);
}

// ---------------- twiddle table (double-computed for accuracy) ----------------
__global__ void k_tw(){
    int j = threadIdx.x;                        // 512 threads
    double a = -2.0*3.14159265358979323846*(double)j/512.0;
    g_tw[j] = make_float2((float)cos(a), (float)sin(a));
}

template<bool INV>
__device__ __forceinline__ cpx twmul(cpx a, int k){
    cpx w = g_tw[k & 511];
    if (INV) w.y = -w.y;
    return cmul(a, w);
}

// ---------------- radix-4 DIF butterfly (in-register) ----------------
template<bool INV>
__device__ __forceinline__ void dft4(cpx* x){
    cpx e0 = cadd(x[0], x[2]), e1 = csub(x[0], x[2]);
    cpx o0 = cadd(x[1], x[3]), o1 = csub(x[1], x[3]);
    x[0] = cadd(e0, o0);
    x[2] = csub(e0, o0);
    if (!INV){ x[1] = make_float2(e1.x + o1.y, e1.y - o1.x);
               x[3] = make_float2(e1.x - o1.y, e1.y + o1.x); }
    else     { x[1] = make_float2(e1.x - o1.y, e1.y + o1.x);
               x[3] = make_float2(e1.x + o1.y, e1.y - o1.x); }
}

// ---------------- radix-8 DIF butterfly (in-register) ----------------
template<bool INV>
__device__ __forceinline__ void dft8(cpx* x){
    const float s = 0.70710678118654752440f;
    cpx e0 = cadd(x[0], x[4]), e2 = csub(x[0], x[4]);
    cpx e1 = cadd(x[2], x[6]), e3 = csub(x[2], x[6]);
    cpx E0 = cadd(e0, e1), E2 = csub(e0, e1);
    cpx E1, E3;
    if (!INV){ E1 = make_float2(e2.x + e3.y, e2.y - e3.x);
               E3 = make_float2(e2.x - e3.y, e2.y + e3.x); }
    else     { E1 = make_float2(e2.x - e3.y, e2.y + e3.x);
               E3 = make_float2(e2.x + e3.y, e2.y - e3.x); }
    cpx o0 = cadd(x[1], x[5]), o2 = csub(x[1], x[5]);
    cpx o1 = cadd(x[3], x[7]), o3 = csub(x[3], x[7]);
    cpx O0 = cadd(o0, o1), O2 = csub(o0, o1);
    cpx O1, O3;
    if (!INV){ O1 = make_float2(o2.x + o3.y, o2.y - o3.x);
               O3 = make_float2(o2.x - o3.y, o2.y + o3.x); }
    else     { O1 = make_float2(o2.x - o3.y, o2.y + o3.x);
               O3 = make_float2(o2.x + o3.y, o2.y - o3.x); }
    cpx W1, W2, W3;
    if (!INV){
        W1 = make_float2(s*(O1.x + O1.y), s*(O1.y - O1.x));
        W2 = make_float2(O2.y, -O2.x);
        W3 = make_float2(s*(O3.y - O3.x), -s*(O3.x + O3.y));
    } else {
        W1 = make_float2(s*(O1.x - O1.y), s*(O1.x + O1.y));
        W2 = make_float2(-O2.y, O2.x);
        W3 = make_float2(-s*(O3.x + O3.y), s*(O3.x - O3.y));
    }
    x[0] = cadd(E0, O0); x[4] = csub(E0, O0);
    x[1] = cadd(E1, W1); x[5] = csub(E1, W1);
    x[2] = cadd(E2, W2); x[6] = csub(E2, W2);
    x[3] = cadd(E3, W3); x[7] = csub(E3, W3);
}

// ---------------- 256-pt radix-4 DIF FFT on a contiguous LDS line, 64 thr/line ----------------
// Output left base-4 digit-reversed in LDS (bin k at position rev4_8(k)).
template<bool INV>
__device__ __forceinline__ void fft256_r4(cpx* sl, int b){
    cpx x[4];
    {   // stage 0: stride 64, tw W_512^{2*j*r}
        int j = b;
        #pragma unroll
        for (int t = 0; t < 4; ++t) x[t] = sl[j + (t << 6)];
        dft4<INV>(x);
        #pragma unroll
        for (int r = 1; r < 4; ++r) x[r] = twmul<INV>(x[r], 2*j*r);
        #pragma unroll
        for (int r = 0; r < 4; ++r) sl[j + (r << 6)] = x[r];
    }
    __syncthreads();
    {   // stage 1: stride 16, tw W_512^{8*j*r}
        int j = b & 15, g = (b >> 4) << 6;
        #pragma unroll
        for (int t = 0; t < 4; ++t) x[t] = sl[g + j + (t << 4)];
        dft4<INV>(x);
        #pragma unroll
        for (int r = 1; r < 4; ++r) x[r] = twmul<INV>(x[r], 8*j*r);
        #pragma unroll
        for (int r = 0; r < 4; ++r) sl[g + j + (r << 4)] = x[r];
    }
    __syncthreads();
    {   // stage 2: stride 4, tw W_512^{32*j*r}
        int j = b & 3, g = (b >> 2) << 4;
        #pragma unroll
        for (int t = 0; t < 4; ++t) x[t] = sl[g + j + (t << 2)];
        dft4<INV>(x);
        #pragma unroll
        for (int r = 1; r < 4; ++r) x[r] = twmul<INV>(x[r], 32*j*r);
        #pragma unroll
        for (int r = 0; r < 4; ++r) sl[g + j + (r << 2)] = x[r];
    }
    __syncthreads();
    {   // stage 3: stride 1, no twiddle
        int g = b << 2;
        #pragma unroll
        for (int t = 0; t < 4; ++t) x[t] = sl[g + t];
        dft4<INV>(x);
        #pragma unroll
        for (int r = 0; r < 4; ++r) sl[g + r] = x[r];
    }
    __syncthreads();
}

// ---------------- forward x-FFT fused with fill; store x-fftshifted AND x-half-blurred ----------------
// 4 lines/block. Stored position p gets 0.5*(F_s[p-1]+F_s[p]); F_s[q] = bin(q^128), F_s[-1]=0.
__global__ __launch_bounds__(256) void k_fft_x_fill(const float* __restrict__ feat, cpx* __restrict__ V){
    __shared__ cpx s[4*256];                     // 8 KiB
    int tid = threadIdx.x;
    int line0 = blockIdx.x << 2;                 // line = z*128 + y, z<256, y<128
    {
        int l = tid >> 6, e2 = tid & 63;         // one float2 of feat per thread
        int line = line0 + l;
        int z = line >> 7;
        float g = (float)z*(1.0f/255.0f);
        float2 v = ((const float2*)(feat + ((size_t)line << 7)))[e2];
        float a = v.x*g*g, bb = v.y*g*g;
        a  = a  > 0.0f ? sqrtf(a)  : 0.0f;
        bb = bb > 0.0f ? sqrtf(bb) : 0.0f;
        cpx* sl = s + l*256;
        sl[2*e2]       = make_float2(a, 0.0f);
        sl[2*e2 + 1]   = make_float2(bb, 0.0f);
        sl[128 + 2*e2]     = make_float2(0.0f, 0.0f);
        sl[128 + 2*e2 + 1] = make_float2(0.0f, 0.0f);
    }
    __syncthreads();
    fft256_r4<false>(s + (tid >> 6)*256, tid & 63);
    // blurred shifted store: F_s[e] sits at LDS pos rev4_8(e)^2 (rev4_8(128)=2)
    for (int i = tid; i < 4*128; i += 256){
        int l = i >> 7, f4 = i & 127;
        int line = line0 + l;
        int base = ((line >> 7) << 16) + ((line & 127) << 8);
        const cpx* sl = s + l*256;
        int e0 = 2*f4;
        cpx Fm = e0 ? sl[rev4_8(e0 - 1) ^ 2] : make_float2(0.0f, 0.0f);
        cpx F0 = sl[rev4_8(e0) ^ 2];
        cpx F1 = sl[rev4_8(e0 + 1) ^ 2];
        float4 o;
        o.x = 0.5f*(Fm.x + F0.x); o.y = 0.5f*(Fm.y + F0.y);
        o.z = 0.5f*(F0.x + F1.x); o.w = 0.5f*(F0.y + F1.y);
        ((float4*)(V + base))[f4] = o;
    }
}

// ---------------- final inverse x-FFT fused with |.|^2, crop x<128; 4 lines/block ----------------
__global__ __launch_bounds__(256) void k_fft_x_inv_mag(const cpx* __restrict__ W,
                                                       float* __restrict__ out){
    __shared__ cpx s[4*256];                     // 8 KiB
    int tid = threadIdx.x;
    int line0 = blockIdx.x << 2;
    for (int i = tid; i < 4*128; i += 256){      // load 2 cpx per iteration
        int l = i >> 7, f4 = i & 127;
        int line = line0 + l;
        int base = ((line >> 7) << 16) + ((line & 127) << 8);
        ((float4*)(s + l*256))[f4] = ((const float4*)(W + base))[f4];
    }
    __syncthreads();
    fft256_r4<true>(s + (tid >> 6)*256, tid & 63);
    {
        int l = tid >> 6, e2 = tid & 63;         // two outputs per thread
        int line = line0 + l;
        int z = line >> 7, y = line & 127;
        const cpx* sl = s + l*256;
        cpx v0 = sl[rev4_8(2*e2)];
        cpx v1 = sl[rev4_8(2*e2 + 1)];
        const float SC2 = (1.0f/33554432.0f)*(1.0f/33554432.0f);   // (1/(512*256*256))^2
        float2 o = make_float2((v0.x*v0.x + v0.y*v0.y)*SC2,
                               (v1.x*v1.x + v1.y*v1.y)*SC2);
        ((float2*)(out + (((size_t)(z*128 + y)) << 7)))[e2] = o;
    }
}

// ---------------- FFT along y: 256 pts = 4 radix-4 DIF stages, tile 16 x, fixed z ----------------
// Forward: store y-fftshifted AND y-half-blurred: pos e = 0.5*(F_s[e-1]+F_s[e]), F_s[-1]=0.
// Inverse: plain store, crop y<128.
template<bool INV, bool HALF_IN, bool HALF_OUT>
__global__ __launch_bounds__(1024) void k_fft_y(cpx* __restrict__ V){
    __shared__ cpx s[256*16];                   // 32 KiB
    int tid = threadIdx.x;
    int z  = blockIdx.x >> 4;
    int x0 = (blockIdx.x & 15) << 4;
    int base = (z << 16) + x0;
    const int YIN = HALF_IN ? 128 : 256;
    for (int i = tid; i < YIN*8; i += 1024){     // float4: 8 units of 2 cpx per row
        int f4c = i & 7, e = i >> 3;
        ((float4*)(s + e*16))[f4c] = ((const float4*)(V + base + (e << 8)))[f4c];
    }
    if (HALF_IN){
        for (int i = tid; i < 128*16; i += 1024){
            int c = i & 15, e = (i >> 4) + 128;
            s[e*16 + c] = make_float2(0.0f, 0.0f);
        }
    }
    __syncthreads();
    int c = tid & 15, idx = tid >> 4;
    cpx x[4];
    {   // stage 0: stride 64, tw W_512^{2*j*r}
        int j = idx;
        #pragma unroll
        for (int t = 0; t < 4; ++t) x[t] = s[(j + (t << 6))*16 + c];
        dft4<INV>(x);
        #pragma unroll
        for (int r = 1; r < 4; ++r) x[r] = twmul<INV>(x[r], 2*j*r);
        #pragma unroll
        for (int r = 0; r < 4; ++r) s[(j + (r << 6))*16 + c] = x[r];
    }
    __syncthreads();
    {   // stage 1: stride 16, tw W_512^{8*j*r}
        int j = idx & 15, g = (idx >> 4) << 6;
        #pragma unroll
        for (int t = 0; t < 4; ++t) x[t] = s[(g + j + (t << 4))*16 + c];
        dft4<INV>(x);
        #pragma unroll
        for (int r = 1; r < 4; ++r) x[r] = twmul<INV>(x[r], 8*j*r);
        #pragma unroll
        for (int r = 0; r < 4; ++r) s[(g + j + (r << 4))*16 + c] = x[r];
    }
    __syncthreads();
    {   // stage 2: stride 4, tw W_512^{32*j*r}
        int j = idx & 3, g = (idx >> 2) << 4;
        #pragma unroll
        for (int t = 0; t < 4; ++t) x[t] = s[(g + j + (t << 2))*16 + c];
        dft4<INV>(x);
        #pragma unroll
        for (int r = 1; r < 4; ++r) x[r] = twmul<INV>(x[r], 32*j*r);
        #pragma unroll
        for (int r = 0; r < 4; ++r) s[(g + j + (r << 2))*16 + c] = x[r];
    }
    __syncthreads();
    {   // stage 3: stride 1, no twiddle
        int g = idx << 2;
        #pragma unroll
        for (int t = 0; t < 4; ++t) x[t] = s[(g + t)*16 + c];
        dft4<INV>(x);
        #pragma unroll
        for (int r = 0; r < 4; ++r) s[(g + r)*16 + c] = x[r];
    }
    __syncthreads();
    const int YOUT = HALF_OUT ? 128 : 256;
    for (int i = tid; i < YOUT*8; i += 1024){
        int f4c = i & 7, e = i >> 3;
        if (!INV){
            // blurred shifted store: pos e = 0.5*(F_s[e-1] + F_s[e]); F_s[q] at row rev4(q)^2
            int p0 = rev4_8(e) ^ 2;
            float4 S0 = ((const float4*)(s + p0*16))[f4c];
            float4 S1 = make_float4(0.0f, 0.0f, 0.0f, 0.0f);
            if (e){
                int p1 = rev4_8(e - 1) ^ 2;
                S1 = ((const float4*)(s + p1*16))[f4c];
            }
            float4 o;
            o.x = 0.5f*(S0.x + S1.x); o.y = 0.5f*(S0.y + S1.y);
            o.z = 0.5f*(S0.z + S1.z); o.w = 0.5f*(S0.w + S1.w);
            ((float4*)(V + base + (e << 8)))[f4c] = o;
        } else {
            int p = rev4_8(e);
            ((float4*)(V + base + (e << 8)))[f4c] = ((const float4*)(s + p*16))[f4c];
        }
    }
}

// ---------------- forward FFT along z: 3 radix-8 DIF stages, tile 16 x, fixed y ----------------
// Reads planes 0..255 (zero-pads 256..511), stores bins 0..255 at planes 256..511 (shifted).
__global__ __launch_bounds__(1024) void k_fft_z_fwd(cpx* __restrict__ V){
    __shared__ cpx s[512*16];                   // 64 KiB
    int tid = threadIdx.x;
    int y  = blockIdx.x >> 4;
    int x0 = (blockIdx.x & 15) << 4;
    int base = (y << 8) + x0;
    for (int i = tid; i < 256*8; i += 1024){
        int f4c = i & 7, e = i >> 3;
        ((float4*)(s + e*16))[f4c] = ((const float4*)(V + base + (e << 16)))[f4c];
    }
    for (int i = tid; i < 256*16; i += 1024){
        int c = i & 15, e = (i >> 4) + 256;
        s[e*16 + c] = make_float2(0.0f, 0.0f);
    }
    __syncthreads();
    int c = tid & 15, idx = tid >> 4;
    cpx x[8];
    {   // stage 0: stride 64, tw W_512^{j*r}
        int j = idx;
        #pragma unroll
        for (int t = 0; t < 8; ++t) x[t] = s[(j + (t << 6))*16 + c];
        dft8<false>(x);
        #pragma unroll
        for (int r = 1; r < 8; ++r) x[r] = twmul<false>(x[r], j*r);
        #pragma unroll
        for (int r = 0; r < 8; ++r) s[(j + (r << 6))*16 + c] = x[r];
    }
    __syncthreads();
    {   // stage 1: stride 8, tw W_512^{8*j*r}
        int j = idx & 7, g = (idx >> 3) << 6;
        #pragma unroll
        for (int t = 0; t < 8; ++t) x[t] = s[(g + j + (t << 3))*16 + c];
        dft8<false>(x);
        #pragma unroll
        for (int r = 1; r < 8; ++r) x[r] = twmul<false>(x[r], 8*j*r);
        #pragma unroll
        for (int r = 0; r < 8; ++r) s[(g + j + (r << 3))*16 + c] = x[r];
    }
    __syncthreads();
    {   // stage 2: stride 1, no twiddle
        int g = idx << 3;
        #pragma unroll
        for (int t = 0; t < 8; ++t) x[t] = s[(g + t)*16 + c];
        dft8<false>(x);
        #pragma unroll
        for (int r = 0; r < 8; ++r) s[(g + r)*16 + c] = x[r];
    }
    __syncthreads();
    for (int i = tid; i < 256*8; i += 1024){
        int f4c = i & 7, e = i >> 3;
        int p = ((e & 7) << 6) | (e & 56) | (e >> 6);   // base-8 digit reversal of 9 bits
        ((float4*)(V + base + ((e + 256) << 16)))[f4c] = ((const float4*)(s + p*16))[f4c];
    }
}

// ---------------- z-only Stolt gather from the HBM fwd spectrum (planes 256..511) ----------------
__device__ __forceinline__ cpx zgather_g(const cpx* __restrict__ Vsrc, int zd, float rxy, int srcoff){
    if (!zd) return make_float2(0.0f, 0.0f);     // t[:, :M+1] = 0 plane
    float gz = (float)zd*(1.0f/256.0f);
    float gzn = sqrtf(rxy + gz*gz);
    float iz = ((gzn + 1.0f)*512.0f - 1.0f)*0.5f;
    float fiz = floorf(iz);
    int iz0 = (int)fiz;                          // in [256, ~536)
    float fz = iz - fiz;
    float sc = gz/(gzn + 1e-8f);
    int z0 = iz0 < 511 ? iz0 : 511;
    int z1 = (iz0 + 1) < 511 ? (iz0 + 1) : 511;
    float w0 = (iz0     <= 511) ? (1.0f - fz)*sc : 0.0f;
    float w1 = (iz0 + 1 <= 511) ? fz*sc : 0.0f;
    cpx a = Vsrc[((size_t)z0 << 16) + srcoff];
    cpx b = Vsrc[((size_t)z1 << 16) + srcoff];
    return make_float2(a.x*w0 + b.x*w1, a.y*w0 + b.y*w1);
}

// ---------------- FUSED: z-only Stolt gather + inverse z-FFT, write planes 0..255 ----------------
// Source (planes 256..511) already carries the x/y half-pixel blurs. Disjoint dest -> race-free.
__global__ __launch_bounds__(1024) void k_stolt_fftz_inv(const cpx* __restrict__ Vsrc, cpx* __restrict__ V){
    __shared__ cpx s[512*16];                   // 64 KiB
    int tid = threadIdx.x;
    int y  = blockIdx.x >> 4;
    int x0 = (blockIdx.x & 15) << 4;
    int base = (y << 8) + x0;
    int c = tid & 15;
    int xd = x0 + c;
    int xs = (xd + 128) & 255;
    int ys = (y + 128) & 255;
    float gx = (float)(xs - 128)*(1.0f/128.0f);
    float gy = (float)(ys - 128)*(1.0f/128.0f);
    float rxy = 0.1024f*(gx*gx + gy*gy);
    int srcoff = (ys << 8) + xs;
    #pragma unroll 4
    for (int i = tid; i < 256*16; i += 1024){
        int zd = i >> 4;
        s[i] = zgather_g(Vsrc, zd, rxy, srcoff);    // s[zd*16 + c]
    }
    for (int i = tid; i < 256*16; i += 1024){
        int cc = i & 15, e = (i >> 4) + 256;
        s[e*16 + cc] = make_float2(0.0f, 0.0f);
    }
    __syncthreads();
    int idx = tid >> 4;
    cpx x[8];
    {   // stage 0
        int j = idx;
        #pragma unroll
        for (int t = 0; t < 8; ++t) x[t] = s[(j + (t << 6))*16 + c];
        dft8<true>(x);
        #pragma unroll
        for (int r = 1; r < 8; ++r) x[r] = twmul<true>(x[r], j*r);
        #pragma unroll
        for (int r = 0; r < 8; ++r) s[(j + (r << 6))*16 + c] = x[r];
    }
    __syncthreads();
    {   // stage 1
        int j = idx & 7, g = (idx >> 3) << 6;
        #pragma unroll
        for (int t = 0; t < 8; ++t) x[t] = s[(g + j + (t << 3))*16 + c];
        dft8<true>(x);
        #pragma unroll
        for (int r = 1; r < 8; ++r) x[r] = twmul<true>(x[r], 8*j*r);
        #pragma unroll
        for (int r = 0; r < 8; ++r) s[(g + j + (r << 3))*16 + c] = x[r];
    }
    __syncthreads();
    {   // stage 2
        int g = idx << 3;
        #pragma unroll
        for (int t = 0; t < 8; ++t) x[t] = s[(g + t)*16 + c];
        dft8<true>(x);
        #pragma unroll
        for (int r = 0; r < 8; ++r) s[(g + r)*16 + c] = x[r];
    }
    __syncthreads();
    for (int i = tid; i < 256*8; i += 1024){
        int f4c = i & 7, e = i >> 3;
        int p = ((e & 7) << 6) | (e & 56) | (e >> 6);
        ((float4*)(V + base + (e << 16)))[f4c] = ((const float4*)(s + p*16))[f4c];
    }
}

extern "C" void kernel_launch(void* const* d_in, const int* in_sizes, int n_in,
                              void* d_out, int out_size, void* d_ws, size_t ws_size,
                              hipStream_t stream){
    const float* feat = (const float*)d_in[0];   // [1,1,256,128,128] f32; tbes=0, tens=256
    float* out = (float*)d_out;                  // [1,1,256,128,128] f32

    const size_t WS_NEED = (size_t)512*256*256*8;   // 268,435,456 B exactly
    if (ws_size < WS_NEED){
        hipMemsetAsync(d_out, 0, (size_t)out_size*sizeof(float), stream);
        return;
    }
    cpx* V = (cpx*)d_ws;

    k_tw<<<1, 512, 0, stream>>>();
    // forward x (+fill,+x-blur) and y (+y-blur), stored fftshifted, planes 0..255
    k_fft_x_fill<<<8192, 256, 0, stream>>>(feat, V);                // 4 lines/block
    k_fft_y<false, true, false><<<4096, 1024, 0, stream>>>(V);      // z<256; y<128 in, blurred y out
    // z stage split (fusion variants lose to this — rounds 7/8)
    k_fft_z_fwd<<<4096, 1024, 0, stream>>>(V);                      // planes 0..255 -> 256..511
    k_stolt_fftz_inv<<<4096, 1024, 0, stream>>>(V, V);              // gather + inv z -> planes 0..255
    // inverse y + inverse x (+|.|^2) with crops
    k_fft_y<true, false, true><<<4096, 1024, 0, stream>>>(V);       // full y in, y<128 out
    k_fft_x_inv_mag<<<8192, 256, 0, stream>>>(V, out);              // 4 lines/block, |.|^2, x<128
}

// Round 10
// 269.898 us; speedup vs baseline: 1.2304x; 1.0419x over previous
//
#include <hip/hip_runtime.h>

// LCT FK-migration: 3D FFT(512,256,256) -> Stolt trilinear resample -> 3D IFFT -> |.|^2
// Single 256 MiB workspace buffer V = [512][256][256] cpx, flat (z<<16)+(y<<8)+x.
// x/y spectra stored FFTSHIFTED with the half-pixel Stolt x/y blurs folded into the
// forward x/y FFT stores (ix = xs-0.5, iy = ys-0.5 exactly => fx=fy=0.5 fixed blur).
// Z-stage SPLIT (fusion variants lost — rounds 7/8): k_fft_z_fwd writes shifted
// z-spectrum to planes 256..511; k_stolt_fftz_inv does z-only gather + inverse z-FFT
// into planes 0..255. Inverse y (crop y<128) and inverse x + |.|^2 (crop x<128) finish.
// Round-10: half-zero-input first-stage (dft8_h4/dft4_h2) and half-needed-output
// last-stage (dft8_lo4/dft4_lo2) specializations; all LDS zero-fill loops removed.

typedef float2 cpx;

__device__ float2 g_tw[512];   // exp(-2*pi*i*k/512), k in [0,512)

__device__ __forceinline__ cpx cadd(cpx a, cpx b){ return make_float2(a.x+b.x, a.y+b.y); }
__device__ __forceinline__ cpx csub(cpx a, cpx b){ return make_float2(a.x-b.x, a.y-b.y); }
__device__ __forceinline__ cpx cmul(cpx a, cpx b){ return make_float2(a.x*b.x - a.y*b.y, a.x*b.y + a.y*b.x); }

// base-4 digit reversal of an 8-bit index
__device__ __forceinline__ int rev4_8(int k){
    return ((k & 3) << 6) | ((k & 12) << 2) | ((k >> 2) & 12) | (k >> 6);
}

// ---------------- twiddle table (double-computed for accuracy) ----------------
__global__ void k_tw(){
    int j = threadIdx.x;                        // 512 threads
    double a = -2.0*3.14159265358979323846*(double)j/512.0;
    g_tw[j] = make_float2((float)cos(a), (float)sin(a));
}

template<bool INV>
__device__ __forceinline__ cpx twmul(cpx a, int k){
    cpx w = g_tw[k & 511];
    if (INV) w.y = -w.y;
    return cmul(a, w);
}

// ---------------- radix-4 DIF butterfly (in-register), full ----------------
template<bool INV>
__device__ __forceinline__ void dft4(cpx* x){
    cpx e0 = cadd(x[0], x[2]), e1 = csub(x[0], x[2]);
    cpx o0 = cadd(x[1], x[3]), o1 = csub(x[1], x[3]);
    x[0] = cadd(e0, o0);
    x[2] = csub(e0, o0);
    if (!INV){ x[1] = make_float2(e1.x + o1.y, e1.y - o1.x);
               x[3] = make_float2(e1.x - o1.y, e1.y + o1.x); }
    else     { x[1] = make_float2(e1.x - o1.y, e1.y + o1.x);
               x[3] = make_float2(e1.x + o1.y, e1.y - o1.x); }
}

// radix-4 with x[2]=x[3]=0 (half-support input): inputs in x[0],x[1]
template<bool INV>
__device__ __forceinline__ void dft4_h2(cpx* x){
    cpx a0 = x[0], a1 = x[1];
    x[0] = cadd(a0, a1);
    x[2] = csub(a0, a1);
    if (!INV){ x[1] = make_float2(a0.x + a1.y, a0.y - a1.x);
               x[3] = make_float2(a0.x - a1.y, a0.y + a1.x); }
    else     { x[1] = make_float2(a0.x - a1.y, a0.y + a1.x);
               x[3] = make_float2(a0.x + a1.y, a0.y - a1.x); }
}

// radix-4 computing only outputs 0,1 (the '+' half, natural index bit-high = 0)
template<bool INV>
__device__ __forceinline__ void dft4_lo2(cpx* x){
    cpx e0 = cadd(x[0], x[2]), e1 = csub(x[0], x[2]);
    cpx o0 = cadd(x[1], x[3]), o1 = csub(x[1], x[3]);
    x[0] = cadd(e0, o0);
    if (!INV) x[1] = make_float2(e1.x + o1.y, e1.y - o1.x);
    else      x[1] = make_float2(e1.x - o1.y, e1.y + o1.x);
}

// ---------------- radix-8 DIF butterfly (in-register), full ----------------
template<bool INV>
__device__ __forceinline__ void dft8(cpx* x){
    const float s = 0.70710678118654752440f;
    cpx e0 = cadd(x[0], x[4]), e2 = csub(x[0], x[4]);
    cpx e1 = cadd(x[2], x[6]), e3 = csub(x[2], x[6]);
    cpx E0 = cadd(e0, e1), E2 = csub(e0, e1);
    cpx E1, E3;
    if (!INV){ E1 = make_float2(e2.x + e3.y, e2.y - e3.x);
               E3 = make_float2(e2.x - e3.y, e2.y + e3.x); }
    else     { E1 = make_float2(e2.x - e3.y, e2.y + e3.x);
               E3 = make_float2(e2.x + e3.y, e2.y - e3.x); }
    cpx o0 = cadd(x[1], x[5]), o2 = csub(x[1], x[5]);
    cpx o1 = cadd(x[3], x[7]), o3 = csub(x[3], x[7]);
    cpx O0 = cadd(o0, o1), O2 = csub(o0, o1);
    cpx O1, O3;
    if (!INV){ O1 = make_float2(o2.x + o3.y, o2.y - o3.x);
               O3 = make_float2(o2.x - o3.y, o2.y + o3.x); }
    else     { O1 = make_float2(o2.x - o3.y, o2.y + o3.x);
               O3 = make_float2(o2.x + o3.y, o2.y - o3.x); }
    cpx W1, W2, W3;
    if (!INV){
        W1 = make_float2(s*(O1.x + O1.y), s*(O1.y - O1.x));
        W2 = make_float2(O2.y, -O2.x);
        W3 = make_float2(s*(O3.y - O3.x), -s*(O3.x + O3.y));
    } else {
        W1 = make_float2(s*(O1.x - O1.y), s*(O1.x + O1.y));
        W2 = make_float2(-O2.y, O2.x);
        W3 = make_float2(-s*(O3.x + O3.y), s*(O3.x - O3.y));
    }
    x[0] = cadd(E0, O0); x[4] = csub(E0, O0);
    x[1] = cadd(E1, W1); x[5] = csub(E1, W1);
    x[2] = cadd(E2, W2); x[6] = csub(E2, W2);
    x[3] = cadd(E3, W3); x[7] = csub(E3, W3);
}

// radix-8 with x[4..7]=0: inputs in x[0..3], writes all 8 outputs
template<bool INV>
__device__ __forceinline__ void dft8_h4(cpx* x){
    const float s = 0.70710678118654752440f;
    cpx a0 = x[0], a1 = x[1], a2 = x[2], a3 = x[3];
    cpx E0 = cadd(a0, a2), E2 = csub(a0, a2);
    cpx E1, E3, O1, O3;
    if (!INV){
        E1 = make_float2(a0.x + a2.y, a0.y - a2.x);
        E3 = make_float2(a0.x - a2.y, a0.y + a2.x);
        O1 = make_float2(a1.x + a3.y, a1.y - a3.x);
        O3 = make_float2(a1.x - a3.y, a1.y + a3.x);
    } else {
        E1 = make_float2(a0.x - a2.y, a0.y + a2.x);
        E3 = make_float2(a0.x + a2.y, a0.y - a2.x);
        O1 = make_float2(a1.x - a3.y, a1.y + a3.x);
        O3 = make_float2(a1.x + a3.y, a1.y - a3.x);
    }
    cpx O0 = cadd(a1, a3), O2 = csub(a1, a3);
    cpx W1, W2, W3;
    if (!INV){
        W1 = make_float2(s*(O1.x + O1.y), s*(O1.y - O1.x));
        W2 = make_float2(O2.y, -O2.x);
        W3 = make_float2(s*(O3.y - O3.x), -s*(O3.x + O3.y));
    } else {
        W1 = make_float2(s*(O1.x - O1.y), s*(O1.x + O1.y));
        W2 = make_float2(-O2.y, O2.x);
        W3 = make_float2(-s*(O3.x + O3.y), s*(O3.x - O3.y));
    }
    x[0] = cadd(E0, O0); x[4] = csub(E0, O0);
    x[1] = cadd(E1, W1); x[5] = csub(E1, W1);
    x[2] = cadd(E2, W2); x[6] = csub(E2, W2);
    x[3] = cadd(E3, W3); x[7] = csub(E3, W3);
}

// radix-8 computing only outputs 0..3 (the '+' half, position bit2 = 0)
template<bool INV>
__device__ __forceinline__ void dft8_lo4(cpx* x){
    const float s = 0.70710678118654752440f;
    cpx e0 = cadd(x[0], x[4]), e2 = csub(x[0], x[4]);
    cpx e1 = cadd(x[2], x[6]), e3 = csub(x[2], x[6]);
    cpx E0 = cadd(e0, e1), E2 = csub(e0, e1);
    cpx E1, E3;
    if (!INV){ E1 = make_float2(e2.x + e3.y, e2.y - e3.x);
               E3 = make_float2(e2.x - e3.y, e2.y + e3.x); }
    else     { E1 = make_float2(e2.x - e3.y, e2.y + e3.x);
               E3 = make_float2(e2.x + e3.y, e2.y - e3.x); }
    cpx o0 = cadd(x[1], x[5]), o2 = csub(x[1], x[5]);
    cpx o1 = cadd(x[3], x[7]), o3 = csub(x[3], x[7]);
    cpx O0 = cadd(o0, o1), O2 = csub(o0, o1);
    cpx O1, O3;
    if (!INV){ O1 = make_float2(o2.x + o3.y, o2.y - o3.x);
               O3 = make_float2(o2.x - o3.y, o2.y + o3.x); }
    else     { O1 = make_float2(o2.x - o3.y, o2.y + o3.x);
               O3 = make_float2(o2.x + o3.y, o2.y - o3.x); }
    cpx W1, W2, W3;
    if (!INV){
        W1 = make_float2(s*(O1.x + O1.y), s*(O1.y - O1.x));
        W2 = make_float2(O2.y, -O2.x);
        W3 = make_float2(s*(O3.y - O3.x), -s*(O3.x + O3.y));
    } else {
        W1 = make_float2(s*(O1.x - O1.y), s*(O1.x + O1.y));
        W2 = make_float2(-O2.y, O2.x);
        W3 = make_float2(-s*(O3.x + O3.y), s*(O3.x - O3.y));
    }
    x[0] = cadd(E0, O0);
    x[1] = cadd(E1, W1);
    x[2] = cadd(E2, W2);
    x[3] = cadd(E3, W3);
}

// ---------------- 256-pt radix-4 DIF FFT on a contiguous LDS line, 64 thr/line ----------------
// Output left base-4 digit-reversed in LDS (bin k at position rev4_8(k)).
// HIN: input support [0,128) (skips reading upper half). CROP: only natural outputs
// <128 are produced (positions with bit1=0, i.e. g,g+1 of each last-stage butterfly).
template<bool INV, bool HIN, bool CROP>
__device__ __forceinline__ void fft256_r4(cpx* sl, int b){
    cpx x[4];
    {   // stage 0: stride 64, tw W_512^{2*j*r}
        int j = b;
        if (HIN){
            x[0] = sl[j]; x[1] = sl[j + 64];
            dft4_h2<INV>(x);
        } else {
            #pragma unroll
            for (int t = 0; t < 4; ++t) x[t] = sl[j + (t << 6)];
            dft4<INV>(x);
        }
        #pragma unroll
        for (int r = 1; r < 4; ++r) x[r] = twmul<INV>(x[r], 2*j*r);
        #pragma unroll
        for (int r = 0; r < 4; ++r) sl[j + (r << 6)] = x[r];
    }
    __syncthreads();
    {   // stage 1: stride 16, tw W_512^{8*j*r}
        int j = b & 15, g = (b >> 4) << 6;
        #pragma unroll
        for (int t = 0; t < 4; ++t) x[t] = sl[g + j + (t << 4)];
        dft4<INV>(x);
        #pragma unroll
        for (int r = 1; r < 4; ++r) x[r] = twmul<INV>(x[r], 8*j*r);
        #pragma unroll
        for (int r = 0; r < 4; ++r) sl[g + j + (r << 4)] = x[r];
    }
    __syncthreads();
    {   // stage 2: stride 4, tw W_512^{32*j*r}
        int j = b & 3, g = (b >> 2) << 4;
        #pragma unroll
        for (int t = 0; t < 4; ++t) x[t] = sl[g + j + (t << 2)];
        dft4<INV>(x);
        #pragma unroll
        for (int r = 1; r < 4; ++r) x[r] = twmul<INV>(x[r], 32*j*r);
        #pragma unroll
        for (int r = 0; r < 4; ++r) sl[g + j + (r << 2)] = x[r];
    }
    __syncthreads();
    {   // stage 3: stride 1, no twiddle
        int g = b << 2;
        #pragma unroll
        for (int t = 0; t < 4; ++t) x[t] = sl[g + t];
        if (CROP){
            dft4_lo2<INV>(x);
            sl[g] = x[0]; sl[g + 1] = x[1];
        } else {
            dft4<INV>(x);
            #pragma unroll
            for (int r = 0; r < 4; ++r) sl[g + r] = x[r];
        }
    }
    __syncthreads();
}

// ---------------- forward x-FFT fused with fill; store x-fftshifted AND x-half-blurred ----------------
// 4 lines/block. Stored position p gets 0.5*(F_s[p-1]+F_s[p]); F_s[q] = bin(q^128), F_s[-1]=0.
__global__ __launch_bounds__(256) void k_fft_x_fill(const float* __restrict__ feat, cpx* __restrict__ V){
    __shared__ cpx s[4*256];                     // 8 KiB
    int tid = threadIdx.x;
    int line0 = blockIdx.x << 2;                 // line = z*128 + y, z<256, y<128
    {
        int l = tid >> 6, e2 = tid & 63;         // one float2 of feat per thread
        int line = line0 + l;
        int z = line >> 7;
        float g = (float)z*(1.0f/255.0f);
        float2 v = ((const float2*)(feat + ((size_t)line << 7)))[e2];
        float a = v.x*g*g, bb = v.y*g*g;
        a  = a  > 0.0f ? sqrtf(a)  : 0.0f;
        bb = bb > 0.0f ? sqrtf(bb) : 0.0f;
        cpx* sl = s + l*256;
        sl[2*e2]     = make_float2(a, 0.0f);
        sl[2*e2 + 1] = make_float2(bb, 0.0f);
    }
    __syncthreads();
    fft256_r4<false, true, false>(s + (tid >> 6)*256, tid & 63);
    // blurred shifted store: F_s[e] sits at LDS pos rev4_8(e)^2 (rev4_8(128)=2)
    for (int i = tid; i < 4*128; i += 256){
        int l = i >> 7, f4 = i & 127;
        int line = line0 + l;
        int base = ((line >> 7) << 16) + ((line & 127) << 8);
        const cpx* sl = s + l*256;
        int e0 = 2*f4;
        cpx Fm = e0 ? sl[rev4_8(e0 - 1) ^ 2] : make_float2(0.0f, 0.0f);
        cpx F0 = sl[rev4_8(e0) ^ 2];
        cpx F1 = sl[rev4_8(e0 + 1) ^ 2];
        float4 o;
        o.x = 0.5f*(Fm.x + F0.x); o.y = 0.5f*(Fm.y + F0.y);
        o.z = 0.5f*(F0.x + F1.x); o.w = 0.5f*(F0.y + F1.y);
        ((float4*)(V + base))[f4] = o;
    }
}

// ---------------- final inverse x-FFT fused with |.|^2, crop x<128; 4 lines/block ----------------
__global__ __launch_bounds__(256) void k_fft_x_inv_mag(const cpx* __restrict__ W,
                                                       float* __restrict__ out){
    __shared__ cpx s[4*256];                     // 8 KiB
    int tid = threadIdx.x;
    int line0 = blockIdx.x << 2;
    for (int i = tid; i < 4*128; i += 256){      // load 2 cpx per iteration
        int l = i >> 7, f4 = i & 127;
        int line = line0 + l;
        int base = ((line >> 7) << 16) + ((line & 127) << 8);
        ((float4*)(s + l*256))[f4] = ((const float4*)(W + base))[f4];
    }
    __syncthreads();
    fft256_r4<true, false, true>(s + (tid >> 6)*256, tid & 63);
    {
        int l = tid >> 6, e2 = tid & 63;         // two outputs per thread
        int line = line0 + l;
        int z = line >> 7, y = line & 127;
        const cpx* sl = s + l*256;
        cpx v0 = sl[rev4_8(2*e2)];
        cpx v1 = sl[rev4_8(2*e2 + 1)];
        const float SC2 = (1.0f/33554432.0f)*(1.0f/33554432.0f);   // (1/(512*256*256))^2
        float2 o = make_float2((v0.x*v0.x + v0.y*v0.y)*SC2,
                               (v1.x*v1.x + v1.y*v1.y)*SC2);
        ((float2*)(out + (((size_t)(z*128 + y)) << 7)))[e2] = o;
    }
}

// ---------------- FFT along y: 256 pts = 4 radix-4 DIF stages, tile 16 x, fixed z ----------------
// Forward (HALF_IN): input support y<128 -> stage-0 dft4_h2, no zero-fill; store
// y-fftshifted AND y-half-blurred. Inverse (HALF_OUT): stage-3 dft4_lo2, crop y<128.
template<bool INV, bool HALF_IN, bool HALF_OUT>
__global__ __launch_bounds__(1024) void k_fft_y(cpx* __restrict__ V){
    __shared__ cpx s[256*16];                   // 32 KiB
    int tid = threadIdx.x;
    int z  = blockIdx.x >> 4;
    int x0 = (blockIdx.x & 15) << 4;
    int base = (z << 16) + x0;
    const int YIN = HALF_IN ? 128 : 256;
    for (int i = tid; i < YIN*8; i += 1024){     // float4: 8 units of 2 cpx per row
        int f4c = i & 7, e = i >> 3;
        ((float4*)(s + e*16))[f4c] = ((const float4*)(V + base + (e << 8)))[f4c];
    }
    __syncthreads();
    int c = tid & 15, idx = tid >> 4;
    cpx x[4];
    {   // stage 0: stride 64, tw W_512^{2*j*r}
        int j = idx;
        if (HALF_IN){
            x[0] = s[j*16 + c]; x[1] = s[(j + 64)*16 + c];
            dft4_h2<INV>(x);
        } else {
            #pragma unroll
            for (int t = 0; t < 4; ++t) x[t] = s[(j + (t << 6))*16 + c];
            dft4<INV>(x);
        }
        #pragma unroll
        for (int r = 1; r < 4; ++r) x[r] = twmul<INV>(x[r], 2*j*r);
        #pragma unroll
        for (int r = 0; r < 4; ++r) s[(j + (r << 6))*16 + c] = x[r];
    }
    __syncthreads();
    {   // stage 1: stride 16, tw W_512^{8*j*r}
        int j = idx & 15, g = (idx >> 4) << 6;
        #pragma unroll
        for (int t = 0; t < 4; ++t) x[t] = s[(g + j + (t << 4))*16 + c];
        dft4<INV>(x);
        #pragma unroll
        for (int r = 1; r < 4; ++r) x[r] = twmul<INV>(x[r], 8*j*r);
        #pragma unroll
        for (int r = 0; r < 4; ++r) s[(g + j + (r << 4))*16 + c] = x[r];
    }
    __syncthreads();
    {   // stage 2: stride 4, tw W_512^{32*j*r}
        int j = idx & 3, g = (idx >> 2) << 4;
        #pragma unroll
        for (int t = 0; t < 4; ++t) x[t] = s[(g + j + (t << 2))*16 + c];
        dft4<INV>(x);
        #pragma unroll
        for (int r = 1; r < 4; ++r) x[r] = twmul<INV>(x[r], 32*j*r);
        #pragma unroll
        for (int r = 0; r < 4; ++r) s[(g + j + (r << 2))*16 + c] = x[r];
    }
    __syncthreads();
    {   // stage 3: stride 1, no twiddle
        int g = idx << 2;
        #pragma unroll
        for (int t = 0; t < 4; ++t) x[t] = s[(g + t)*16 + c];
        if (HALF_OUT){
            dft4_lo2<INV>(x);                    // only natural <128 needed (pos bit1=0)
            s[g*16 + c] = x[0]; s[(g + 1)*16 + c] = x[1];
        } else {
            dft4<INV>(x);
            #pragma unroll
            for (int r = 0; r < 4; ++r) s[(g + r)*16 + c] = x[r];
        }
    }
    __syncthreads();
    const int YOUT = HALF_OUT ? 128 : 256;
    for (int i = tid; i < YOUT*8; i += 1024){
        int f4c = i & 7, e = i >> 3;
        if (!INV){
            // blurred shifted store: pos e = 0.5*(F_s[e-1] + F_s[e]); F_s[q] at row rev4(q)^2
            int p0 = rev4_8(e) ^ 2;
            float4 S0 = ((const float4*)(s + p0*16))[f4c];
            float4 S1 = make_float4(0.0f, 0.0f, 0.0f, 0.0f);
            if (e){
                int p1 = rev4_8(e - 1) ^ 2;
                S1 = ((const float4*)(s + p1*16))[f4c];
            }
            float4 o;
            o.x = 0.5f*(S0.x + S1.x); o.y = 0.5f*(S0.y + S1.y);
            o.z = 0.5f*(S0.z + S1.z); o.w = 0.5f*(S0.w + S1.w);
            ((float4*)(V + base + (e << 8)))[f4c] = o;
        } else {
            int p = rev4_8(e);
            ((float4*)(V + base + (e << 8)))[f4c] = ((const float4*)(s + p*16))[f4c];
        }
    }
}

// ---------------- forward FFT along z: 3 radix-8 DIF stages, tile 16 x, fixed y ----------------
// Input support planes 0..255 (stage-0 dft8_h4, no zero-fill); output bins 0..255 only
// (stage-2 dft8_lo4) stored at planes 256..511 (shifted).
__global__ __launch_bounds__(1024) void k_fft_z_fwd(cpx* __restrict__ V){
    __shared__ cpx s[512*16];                   // 64 KiB
    int tid = threadIdx.x;
    int y  = blockIdx.x >> 4;
    int x0 = (blockIdx.x & 15) << 4;
    int base = (y << 8) + x0;
    for (int i = tid; i < 256*8; i += 1024){
        int f4c = i & 7, e = i >> 3;
        ((float4*)(s + e*16))[f4c] = ((const float4*)(V + base + (e << 16)))[f4c];
    }
    __syncthreads();
    int c = tid & 15, idx = tid >> 4;
    cpx x[8];
    {   // stage 0: stride 64, inputs rows j+64t (t<4 nonzero), tw W_512^{j*r}
        int j = idx;
        #pragma unroll
        for (int t = 0; t < 4; ++t) x[t] = s[(j + (t << 6))*16 + c];
        dft8_h4<false>(x);
        #pragma unroll
        for (int r = 1; r < 8; ++r) x[r] = twmul<false>(x[r], j*r);
        #pragma unroll
        for (int r = 0; r < 8; ++r) s[(j + (r << 6))*16 + c] = x[r];
    }
    __syncthreads();
    {   // stage 1: stride 8, tw W_512^{8*j*r}
        int j = idx & 7, g = (idx >> 3) << 6;
        #pragma unroll
        for (int t = 0; t < 8; ++t) x[t] = s[(g + j + (t << 3))*16 + c];
        dft8<false>(x);
        #pragma unroll
        for (int r = 1; r < 8; ++r) x[r] = twmul<false>(x[r], 8*j*r);
        #pragma unroll
        for (int r = 0; r < 8; ++r) s[(g + j + (r << 3))*16 + c] = x[r];
    }
    __syncthreads();
    {   // stage 2: stride 1, no twiddle; only '+'-half outputs needed (pos bit2=0)
        int g = idx << 3;
        #pragma unroll
        for (int t = 0; t < 8; ++t) x[t] = s[(g + t)*16 + c];
        dft8_lo4<false>(x);
        #pragma unroll
        for (int r = 0; r < 4; ++r) s[(g + r)*16 + c] = x[r];
    }
    __syncthreads();
    for (int i = tid; i < 256*8; i += 1024){
        int f4c = i & 7, e = i >> 3;
        int p = ((e & 7) << 6) | (e & 56) | (e >> 6);   // base-8 digit reversal (bit2 always 0)
        ((float4*)(V + base + ((e + 256) << 16)))[f4c] = ((const float4*)(s + p*16))[f4c];
    }
}

// ---------------- z-only Stolt gather from the HBM fwd spectrum (planes 256..511) ----------------
__device__ __forceinline__ cpx zgather_g(const cpx* __restrict__ Vsrc, int zd, float rxy, int srcoff){
    if (!zd) return make_float2(0.0f, 0.0f);     // t[:, :M+1] = 0 plane
    float gz = (float)zd*(1.0f/256.0f);
    float gzn = sqrtf(rxy + gz*gz);
    float iz = ((gzn + 1.0f)*512.0f - 1.0f)*0.5f;
    float fiz = floorf(iz);
    int iz0 = (int)fiz;                          // in [256, ~536)
    float fz = iz - fiz;
    float sc = gz/(gzn + 1e-8f);
    int z0 = iz0 < 511 ? iz0 : 511;
    int z1 = (iz0 + 1) < 511 ? (iz0 + 1) : 511;
    float w0 = (iz0     <= 511) ? (1.0f - fz)*sc : 0.0f;
    float w1 = (iz0 + 1 <= 511) ? fz*sc : 0.0f;
    cpx a = Vsrc[((size_t)z0 << 16) + srcoff];
    cpx b = Vsrc[((size_t)z1 << 16) + srcoff];
    return make_float2(a.x*w0 + b.x*w1, a.y*w0 + b.y*w1);
}

// ---------------- FUSED: z-only Stolt gather + inverse z-FFT, write planes 0..255 ----------------
// Gathered support zd<256 (stage-0 dft8_h4, no zero-fill); crop z<256 (stage-2 dft8_lo4).
__global__ __launch_bounds__(1024) void k_stolt_fftz_inv(const cpx* __restrict__ Vsrc, cpx* __restrict__ V){
    __shared__ cpx s[512*16];                   // 64 KiB
    int tid = threadIdx.x;
    int y  = blockIdx.x >> 4;
    int x0 = (blockIdx.x & 15) << 4;
    int base = (y << 8) + x0;
    int c = tid & 15;
    int xd = x0 + c;
    int xs = (xd + 128) & 255;
    int ys = (y + 128) & 255;
    float gx = (float)(xs - 128)*(1.0f/128.0f);
    float gy = (float)(ys - 128)*(1.0f/128.0f);
    float rxy = 0.1024f*(gx*gx + gy*gy);
    int srcoff = (ys << 8) + xs;
    #pragma unroll 4
    for (int i = tid; i < 256*16; i += 1024){
        int zd = i >> 4;
        s[i] = zgather_g(Vsrc, zd, rxy, srcoff);    // s[zd*16 + c]
    }
    __syncthreads();
    int idx = tid >> 4;
    cpx x[8];
    {   // stage 0: inputs rows j+64t (t<4 nonzero), tw W_512^{-j*r}
        int j = idx;
        #pragma unroll
        for (int t = 0; t < 4; ++t) x[t] = s[(j + (t << 6))*16 + c];
        dft8_h4<true>(x);
        #pragma unroll
        for (int r = 1; r < 8; ++r) x[r] = twmul<true>(x[r], j*r);
        #pragma unroll
        for (int r = 0; r < 8; ++r) s[(j + (r << 6))*16 + c] = x[r];
    }
    __syncthreads();
    {   // stage 1
        int j = idx & 7, g = (idx >> 3) << 6;
        #pragma unroll
        for (int t = 0; t < 8; ++t) x[t] = s[(g + j + (t << 3))*16 + c];
        dft8<true>(x);
        #pragma unroll
        for (int r = 1; r < 8; ++r) x[r] = twmul<true>(x[r], 8*j*r);
        #pragma unroll
        for (int r = 0; r < 8; ++r) s[(g + j + (r << 3))*16 + c] = x[r];
    }
    __syncthreads();
    {   // stage 2: only '+'-half outputs needed (crop z<256, pos bit2=0)
        int g = idx << 3;
        #pragma unroll
        for (int t = 0; t < 8; ++t) x[t] = s[(g + t)*16 + c];
        dft8_lo4<true>(x);
        #pragma unroll
        for (int r = 0; r < 4; ++r) s[(g + r)*16 + c] = x[r];
    }
    __syncthreads();
    for (int i = tid; i < 256*8; i += 1024){
        int f4c = i & 7, e = i >> 3;
        int p = ((e & 7) << 6) | (e & 56) | (e >> 6);   // bit2 always 0
        ((float4*)(V + base + (e << 16)))[f4c] = ((const float4*)(s + p*16))[f4c];
    }
}

extern "C" void kernel_launch(void* const* d_in, const int* in_sizes, int n_in,
                              void* d_out, int out_size, void* d_ws, size_t ws_size,
                              hipStream_t stream){
    const float* feat = (const float*)d_in[0];   // [1,1,256,128,128] f32; tbes=0, tens=256
    float* out = (float*)d_out;                  // [1,1,256,128,128] f32

    const size_t WS_NEED = (size_t)512*256*256*8;   // 268,435,456 B exactly
    if (ws_size < WS_NEED){
        hipMemsetAsync(d_out, 0, (size_t)out_size*sizeof(float), stream);
        return;
    }
    cpx* V = (cpx*)d_ws;

    k_tw<<<1, 512, 0, stream>>>();
    // forward x (+fill,+x-blur) and y (+y-blur), stored fftshifted, planes 0..255
    k_fft_x_fill<<<8192, 256, 0, stream>>>(feat, V);                // 4 lines/block
    k_fft_y<false, true, false><<<4096, 1024, 0, stream>>>(V);      // z<256; y<128 in, blurred y out
    // z stage split (fusion variants lose to this — rounds 7/8)
    k_fft_z_fwd<<<4096, 1024, 0, stream>>>(V);                      // planes 0..255 -> 256..511
    k_stolt_fftz_inv<<<4096, 1024, 0, stream>>>(V, V);              // gather + inv z -> planes 0..255
    // inverse y + inverse x (+|.|^2) with crops
    k_fft_y<true, false, true><<<4096, 1024, 0, stream>>>(V);       // full y in, y<128 out
    k_fft_x_inv_mag<<<8192, 256, 0, stream>>>(V, out);              // 4 lines/block, |.|^2, x<128
}